// Round 21
// baseline (32.077 us; speedup 1.0000x reference)
//
#include <hip/hip_runtime.h>

// PersonalizedPageRankGraphAttentionLayer — MI355X gfx950, round 21
// vs round 20 (31.2us): last two identified latency chains in mega.
//  (1) phase B static 32-slot predicated unroll — the runtime-bound loop forced
//      ~18 serial ds_read latencies (~2.2k cy); now all LDS reads issue up
//      front, only the fma chain (~128 cy) is serial. Same values/order.
//  (2) the 8 initial out-gather HW loads (depend only on nidx_) issue right
//      after the first barrier, hiding under hsum/WBM/phase B/cut.
// Canary: absmax must stay exactly 0.0390625.

typedef unsigned short u16;
typedef unsigned int u32;
typedef float  f32x4  __attribute__((ext_vector_type(4)));
typedef short  s16x8  __attribute__((ext_vector_type(8)));
typedef __bf16 bf16x8 __attribute__((ext_vector_type(8)));

#define NN 2048

__device__ __forceinline__ u16 f2bf(float f) {
    unsigned u = __float_as_uint(f);
    return (u16)((u + 0x7FFFu + ((u >> 16) & 1u)) >> 16);  // RNE
}
__device__ __forceinline__ float bf2f(u16 v) {
    return __uint_as_float(((unsigned)v) << 16);           // exact
}

// ---------------- build: HW GEMM (128) | BM+CSR rows + deg + cbf (2048) -----------
__global__ __launch_bounds__(256, 5)
void build_kernel(const float* __restrict__ adj, const float* __restrict__ h,
                  const float* __restrict__ W, const float* __restrict__ av,
                  unsigned char* __restrict__ BMb, u16* __restrict__ CSRc,
                  int* __restrict__ NL, float* __restrict__ cbf,
                  float* __restrict__ deg,
                  float* __restrict__ HW, float* __restrict__ h1part,
                  float* __restrict__ h2part) {
    __shared__ __align__(16) u16 As[2][64 * 64];
    __shared__ __align__(16) u16 Bs[2][64 * 64];
    __shared__ float red[8];
    const int tid = threadIdx.x, lane = tid & 63, wid = tid >> 6;

    if (blockIdx.x >= 128) {
        // ---- bitmask + CSR row + fused deg/cbf ----
        const int row = blockIdx.x - 128;
        const float* ar = adj + (size_t)row * NN;
        const int j0 = tid * 8;
        f32x4 a0 = *(const f32x4*)(ar + j0), a1 = *(const f32x4*)(ar + j0 + 4);
        float s = a0[0] + a0[1] + a0[2] + a0[3] + a1[0] + a1[1] + a1[2] + a1[3];
        #pragma unroll
        for (int o = 32; o; o >>= 1) s += __shfl_down(s, o);
        if (lane == 0) red[wid] = s;
        __syncthreads();
        const float t = red[0] + red[1] + red[2] + red[3];   // exact integer
        if (tid == 0) {
            deg[row] = t;
            cbf[row] = bf2f(f2bf(0.75f * (1.0f / t)));       // == M's stored value
        }
        unsigned bb = 0;
        #pragma unroll
        for (int j = 0; j < 4; j++) bb |= (a0[j] > 0.f) ? (1u << j) : 0u;
        #pragma unroll
        for (int j = 0; j < 4; j++) bb |= (a1[j] > 0.f) ? (1u << (4 + j)) : 0u;
        BMb[(size_t)row * 256 + lane * 4 + wid] = (unsigned char)bb;

        // ordered compaction (ascending j): 256-thread scan
        int* wsumi = (int*)&Bs[0][0];          // alias (GEMM branch not taken)
        const int cnt = __popc(bb);
        int sc = cnt;
        #pragma unroll
        for (int o = 1; o < 64; o <<= 1) {
            const int tt = __shfl_up(sc, o);
            if (lane >= o) sc += tt;
        }
        if (lane == 63) wsumi[wid] = sc;
        __syncthreads();
        int base = 0;
        #pragma unroll
        for (int w = 0; w < 4; w++) if (w < wid) base += wsumi[w];
        int pos = base + sc - cnt;
        #pragma unroll
        for (int e = 0; e < 8; e++)
            if ((bb & (1u << e)) && pos < 128) CSRc[(size_t)row * 128 + pos++] = (u16)(j0 + e);
        if (tid == 0) {
            int Lt = wsumi[0] + wsumi[1] + wsumi[2] + wsumi[3];
            NL[row] = (Lt > 128) ? 128 : Lt;
        }
        return;
    }

    // ---- HW = h @ W tile (64x64, K=512) with f32->bf16 reg-staging ----
    const int b2 = blockIdx.x;
    const int trow = (b2 >> 2) * 64, tcol = (b2 & 3) * 64;
    const int wrow = (wid >> 1) * 32, wcol = (wid & 1) * 32;
    const int lrow = lane & 15, lq = lane >> 4;

    const int arow = tid >> 2, aq = tid & 3;
    auto stageA = [&](int k0, int buf) {
        const float* hp = h + (size_t)(trow + arow) * 512 + k0 + aq * 16;
        f32x4 v0 = *(const f32x4*)hp;
        f32x4 v1 = *(const f32x4*)(hp + 4);
        f32x4 v2 = *(const f32x4*)(hp + 8);
        f32x4 v3 = *(const f32x4*)(hp + 12);
        union { u16 h[8]; uint4 q; } o0, o1;
        #pragma unroll
        for (int j = 0; j < 4; j++) {
            o0.h[j] = f2bf(v0[j]); o0.h[4 + j] = f2bf(v1[j]);
            o1.h[j] = f2bf(v2[j]); o1.h[4 + j] = f2bf(v3[j]);
        }
        const int g0 = aq * 2;
        *(uint4*)&As[buf][arow * 64 + (g0 ^ (arow & 7)) * 8]       = o0.q;
        *(uint4*)&As[buf][arow * 64 + ((g0 + 1) ^ (arow & 7)) * 8] = o1.q;
    };
    const int bcol = tid >> 2, bq = tid & 3;
    auto stageB = [&](int k0, int buf) {
        union { u16 h[8]; uint4 q; } o0, o1;
        #pragma unroll
        for (int j = 0; j < 8; j++) {
            o0.h[j] = f2bf(W[(size_t)(k0 + bq * 16 + j) * 256 + tcol + bcol]);
            o1.h[j] = f2bf(W[(size_t)(k0 + bq * 16 + 8 + j) * 256 + tcol + bcol]);
        }
        const int g0 = bq * 2;
        *(uint4*)&Bs[buf][bcol * 64 + (g0 ^ (bcol & 7)) * 8]       = o0.q;
        *(uint4*)&Bs[buf][bcol * 64 + ((g0 + 1) ^ (bcol & 7)) * 8] = o1.q;
    };

    f32x4 acc[2][2] = {};
    stageA(0, 0); stageB(0, 0);
    __syncthreads();
    for (int ks = 0; ks < 8; ks++) {
        const int cur = ks & 1;
        if (ks < 7) { stageA((ks + 1) * 64, cur ^ 1); stageB((ks + 1) * 64, cur ^ 1); }
        bf16x8 af[2][2], bfv[2][2];
        #pragma unroll
        for (int kk = 0; kk < 2; kk++) {
            const int gsz = ((kk * 4 + lq) ^ (lrow & 7)) * 8;
            #pragma unroll
            for (int m = 0; m < 2; m++) {
                af[m][kk]  = *(const bf16x8*)&As[cur][(wrow + m * 16 + lrow) * 64 + gsz];
                bfv[m][kk] = *(const bf16x8*)&Bs[cur][(wcol + m * 16 + lrow) * 64 + gsz];
            }
        }
        #pragma unroll
        for (int kk = 0; kk < 2; kk++)
            #pragma unroll
            for (int m = 0; m < 2; m++)
                #pragma unroll
                for (int n = 0; n < 2; n++)
                    acc[m][n] = __builtin_amdgcn_mfma_f32_16x16x32_bf16(
                        af[m][kk], bfv[n][kk], acc[m][n], 0, 0, 0);
        __syncthreads();
    }
    float* hred = (float*)&As[0][0];   // alias (K-loop done, barrier passed)
    const int crow0 = trow + wrow + lq * 4;
    const int ccol0 = tcol + wcol + lrow;
    float av1[2], av2[2];
    #pragma unroll
    for (int n = 0; n < 2; n++) {
        av1[n] = av[ccol0 + n * 16];
        av2[n] = av[256 + ccol0 + n * 16];
    }
    #pragma unroll
    for (int m = 0; m < 2; m++) {
        #pragma unroll
        for (int r = 0; r < 4; r++) {
            float s1 = 0.f, s2 = 0.f;
            #pragma unroll
            for (int n = 0; n < 2; n++) {
                const float v = acc[m][n][r];
                HW[(size_t)(crow0 + m * 16 + r) * 256 + ccol0 + n * 16] = v;
                s1 += v * av1[n];
                s2 += v * av2[n];
            }
            #pragma unroll
            for (int o = 1; o < 16; o <<= 1) {
                s1 += __shfl_xor(s1, o);
                s2 += __shfl_xor(s2, o);
            }
            if (lrow == 0) {
                const int rl = wrow + lq * 4 + m * 16 + r;
                hred[rl * 4 + (wid & 1) * 2 + 0] = s1;
                hred[rl * 4 + (wid & 1) * 2 + 1] = s2;
            }
        }
    }
    __syncthreads();
    if (tid < 64) {
        h1part[(size_t)(b2 & 3) * NN + trow + tid] = hred[tid * 4 + 0] + hred[tid * 4 + 2];
        h2part[(size_t)(b2 & 3) * NN + trow + tid] = hred[tid * 4 + 1] + hred[tid * 4 + 3];
    }
}

// ---------------- wave reduce helpers ----------------
__device__ __forceinline__ int wred_sum_i(int v) {
    #pragma unroll
    for (int o = 32; o; o >>= 1) v += __shfl_down(v, o);
    return __shfl(v, 0);
}
__device__ __forceinline__ float wred_sum_f(float v) {
    #pragma unroll
    for (int o = 32; o; o >>= 1) v += __shfl_down(v, o);
    return __shfl(v, 0);
}
__device__ __forceinline__ float wred_max_f(float v) {
    #pragma unroll
    for (int o = 32; o; o >>= 1) v = fmaxf(v, __shfl_down(v, o));
    return __shfl(v, 0);
}

// ---------------- mega: CSR + LDS-BM neighbor-only P + softmax + out -------------
__global__ __launch_bounds__(64)
void mega_kernel(const u32* __restrict__ BM, const float* __restrict__ cbf,
                 const u16* __restrict__ CSRc, const int* __restrict__ NL,
                 const float* __restrict__ HW,
                 const float* __restrict__ h1p, const float* __restrict__ h2p,
                 const float* __restrict__ degv,
                 const float* __restrict__ a_ppr_p, float* __restrict__ out) {
    __shared__ u32   WBM[32][64];     // 8 KB: neighbor bitmask rows (typ. L<=32)
    __shared__ int   nidx_[128];
    __shared__ float nmv_[128];
    __shared__ float pval_[128];
    __shared__ float nval_[128];
    __shared__ float hsum_[128];
    const int lane = threadIdx.x;
    const int row = blockIdx.x;
    const float wi = cbf[row];
    const int L = NL[row];

    // ---- Phase A: CSR load (parallel, no scan) ----
    const bool vA = (lane < L), vB = (lane + 64 < L);
    int jA = 0, jB = 0;
    if (vA) jA = CSRc[(size_t)row * 128 + lane];
    if (vB) jB = CSRc[(size_t)row * 128 + 64 + lane];
    if (vA) { nidx_[lane] = jA; nmv_[lane] = cbf[jA]; }
    if (vB) { nidx_[lane + 64] = jB; nmv_[lane + 64] = cbf[jB]; }
    __syncthreads();

    // ---- out-gather initial 8 loads: depend only on nidx_ -> issue NOW,
    //      hiding under hsum/WBM/phase B/cut ----
    f32x4 hv0 = {0,0,0,0}, hv1 = {0,0,0,0}, hv2 = {0,0,0,0}, hv3 = {0,0,0,0};
    f32x4 hv4 = {0,0,0,0}, hv5 = {0,0,0,0}, hv6 = {0,0,0,0}, hv7 = {0,0,0,0};
    if (L > 0) hv0 = *(const f32x4*)(HW + (size_t)nidx_[0] * 256 + lane * 4);
    if (L > 1) hv1 = *(const f32x4*)(HW + (size_t)nidx_[1] * 256 + lane * 4);
    if (L > 2) hv2 = *(const f32x4*)(HW + (size_t)nidx_[2] * 256 + lane * 4);
    if (L > 3) hv3 = *(const f32x4*)(HW + (size_t)nidx_[3] * 256 + lane * 4);
    if (L > 4) hv4 = *(const f32x4*)(HW + (size_t)nidx_[4] * 256 + lane * 4);
    if (L > 5) hv5 = *(const f32x4*)(HW + (size_t)nidx_[5] * 256 + lane * 4);
    if (L > 6) hv6 = *(const f32x4*)(HW + (size_t)nidx_[6] * 256 + lane * 4);
    if (L > 7) hv7 = *(const f32x4*)(HW + (size_t)nidx_[7] * 256 + lane * 4);

    // ---- pre-issue h2p gathers (overlap WBM fill + phase B); same add order ----
    if (vA) hsum_[lane]      = h2p[jA] + h2p[NN + jA] + h2p[2 * NN + jA] + h2p[3 * NN + jA];
    if (vB) hsum_[lane + 64] = h2p[jB] + h2p[NN + jB] + h2p[2 * NN + jB] + h2p[3 * NN + jB];
    const float h1r = h1p[row] + h1p[NN + row] + h1p[2 * NN + row] + h1p[3 * NN + row];

    // ---- preload neighbor BM rows: STATIC 32-slot bulk issue into registers ----
    const int Lp = (L < 32) ? L : 32;
    u32 wtmp[32];
    #pragma unroll
    for (int kk = 0; kk < 32; kk++)
        wtmp[kk] = (kk < Lp) ? BM[(size_t)nidx_[kk] * 64 + lane] : 0u;
    #pragma unroll
    for (int kk = 0; kk < 32; kk++)
        if (kk < Lp) WBM[kk][lane] = wtmp[kk];
    __syncthreads();

    // ---- Phase B: per-neighbor P; STATIC 32-slot predicated unroll ----
    const int wAi = (jA >> 3) & 63, bAi = ((jA >> 9) << 3) | (jA & 7);
    const int wBi = (jB >> 3) & 63, bBi = ((jB >> 9) << 3) | (jB & 7);
    float pA = wi; if (vA && jA == row) pA += 1.f;
    float pB = wi; if (vB && jB == row) pB += 1.f;
    #pragma unroll
    for (int kk = 0; kk < 32; kk++) {
        if (kk < Lp) {
            const float ck = nmv_[kk];
            const u32 wordA = WBM[kk][wAi];
            const u32 wordB = WBM[kk][wBi];
            pA = fmaf(wi, ((wordA >> bAi) & 1u) ? ck : 0.f, pA);
            pB = fmaf(wi, ((wordB >> bBi) & 1u) ? ck : 0.f, pB);
        }
    }
    for (int kk = Lp; kk < L; kk++) {          // rare L>32 tail: direct loads
        const float ck = nmv_[kk];
        const u32* rp = BM + (size_t)nidx_[kk] * 64;
        pA = fmaf(wi, ((rp[wAi] >> bAi) & 1u) ? ck : 0.f, pA);
        pB = fmaf(wi, ((rp[wBi] >> bBi) & 1u) ? ck : 0.f, pB);
    }
    pA *= 0.25f; pB *= 0.25f;
    if (vA) pval_[lane] = pA;
    if (vB) pval_[lane + 64] = pB;

    // ---- cut: skip when L<=32; L>32: bisection over neighbor values ----
    float cut = -1.0f;
    int tsel = 32, te = 0;
    if (L > 32) {
        unsigned lo = 0u, hi = 0x40000000u;   // [0, 2.0)
        while (hi - lo > 1u) {
            const unsigned mid = (lo + hi) >> 1;
            const float mf = __uint_as_float(mid);
            int c = (vA && pA >= mf) + (vB && pB >= mf);
            c = wred_sum_i(c);
            if (c >= 32) lo = mid; else hi = mid;
        }
        cut = __uint_as_float(lo);
        int mg = (vA && pA > cut) + (vB && pB > cut);
        int t2 = (vA && pA == cut) + (vB && pB == cut);
        mg = wred_sum_i(mg);
        te = wred_sum_i(t2);
        tsel = 32 - mg;
    }

    __syncthreads();   // pval + hsum visible across lanes

    // ---- e values for neighbors, wave softmax ----
    const float dgr = degv[row];
    const float apr = a_ppr_p[0];
    float mymax = -3.0e38f;
    for (int k = lane; k < L; k += 64) {
        const int j = nidx_[k];
        const float p = pval_[k];
        bool sel = p > cut;
        if (!sel && p == cut) {
            if (tsel >= te) sel = true;
            else {                           // rare: low-index ties over neighbors
                int rk = 0;
                for (int q = 0; q < k; q++) rk += (pval_[q] == cut);
                sel = (rk < tsel);
            }
        }
        const float pprv = sel ? p * sqrtf(dgr / degv[j]) : 0.f;
        float e = h1r + hsum_[k] + apr * pprv;
        e = (e > 0.f) ? e : 0.2f * e;        // leaky_relu 0.2
        nval_[k] = e;
        mymax = fmaxf(mymax, e);
    }
    const float mx = wred_max_f(mymax);
    float mysum = 0.f;
    for (int k = lane; k < L; k += 64) {
        const float ev = expf(nval_[k] - mx);
        nval_[k] = ev;
        mysum += ev;
    }
    const float inv = 1.f / wred_sum_f(mysum);

    __syncthreads();   // nval visible across lanes

    // ---- out[row,:] = sum_k att_k * HW[j_k,:]; 8-deep rotating prefetch ----
    f32x4 acc = {0.f, 0.f, 0.f, 0.f};
    for (int k = 0; k < L; k++) {
        const f32x4 cur = hv0;
        hv0 = hv1; hv1 = hv2; hv2 = hv3; hv3 = hv4;
        hv4 = hv5; hv5 = hv6; hv6 = hv7;
        if (k + 8 < L) hv7 = *(const f32x4*)(HW + (size_t)nidx_[k + 8] * 256 + lane * 4);
        acc += (nval_[k] * inv) * cur;
    }
    *(f32x4*)(out + (size_t)row * 256 + lane * 4) = acc;
}

// ---------------- host ----------------
extern "C" void kernel_launch(void* const* d_in, const int* in_sizes, int n_in,
                              void* d_out, int out_size, void* d_ws, size_t ws_size,
                              hipStream_t stream) {
    const float* h     = (const float*)d_in[0];   // [2048,512]
    const float* adj   = (const float*)d_in[1];   // [2048,2048]
    const float* W     = (const float*)d_in[2];   // [512,256]
    const float* a     = (const float*)d_in[3];   // [512,1]
    const float* a_ppr = (const float*)d_in[4];   // [1,1]
    float* out = (float*)d_out;

    char* ws = (char*)d_ws;
    auto alloc = [&](size_t bytes) { char* p = ws; ws += (bytes + 255) & ~(size_t)255; return p; };
    unsigned char* BMb = (unsigned char*)alloc((size_t)NN * 256);   // 512 KB
    u16*   CSRc   = (u16*)  alloc((size_t)NN * 128 * 2);            // 512 KB
    int*   NL     = (int*)  alloc(NN * 4);
    float* cbf    = (float*)alloc(NN * 4);
    float* HW     = (float*)alloc((size_t)NN * 256 * 4);
    float* deg    = (float*)alloc(NN * 4);
    float* h1part = (float*)alloc((size_t)4 * NN * 4);
    float* h2part = (float*)alloc((size_t)4 * NN * 4);

    build_kernel<<<2176, 256, 0, stream>>>(adj, h, W, a, BMb, CSRc, NL, cbf, deg,
                                           HW, h1part, h2part);
    mega_kernel<<<NN, 64, 0, stream>>>((const u32*)BMb, cbf, CSRc, NL, HW,
                                       h1part, h2part, deg, a_ppr, out);
}

// Round 22
// 31.202 us; speedup vs baseline: 1.0280x; 1.0280x over previous
//
#include <hip/hip_runtime.h>

// PersonalizedPageRankGraphAttentionLayer — MI355X gfx950, round 22
// REVERT to round 20 (best measured: 31.18us, absmax 0.0390625).
// Rounds 19-21 attacked three theorized mega latency chains; all landed within
// the +-1us noise band and r21 slightly regressed -> lock in the best variant.
// Pipeline: build (2176 blocks: HW GEMM | BM+CSR+deg+cbf) -> mega (2048
// one-wave blocks: CSR + LDS-BM neighbor-only P + top-32-skip + softmax + out).
// Canary: absmax exactly 0.0390625.

typedef unsigned short u16;
typedef unsigned int u32;
typedef float  f32x4  __attribute__((ext_vector_type(4)));
typedef short  s16x8  __attribute__((ext_vector_type(8)));
typedef __bf16 bf16x8 __attribute__((ext_vector_type(8)));

#define NN 2048

__device__ __forceinline__ u16 f2bf(float f) {
    unsigned u = __float_as_uint(f);
    return (u16)((u + 0x7FFFu + ((u >> 16) & 1u)) >> 16);  // RNE
}
__device__ __forceinline__ float bf2f(u16 v) {
    return __uint_as_float(((unsigned)v) << 16);           // exact
}

// ---------------- build: HW GEMM (128) | BM+CSR rows + deg + cbf (2048) -----------
__global__ __launch_bounds__(256, 5)
void build_kernel(const float* __restrict__ adj, const float* __restrict__ h,
                  const float* __restrict__ W, const float* __restrict__ av,
                  unsigned char* __restrict__ BMb, u16* __restrict__ CSRc,
                  int* __restrict__ NL, float* __restrict__ cbf,
                  float* __restrict__ deg,
                  float* __restrict__ HW, float* __restrict__ h1part,
                  float* __restrict__ h2part) {
    __shared__ __align__(16) u16 As[2][64 * 64];
    __shared__ __align__(16) u16 Bs[2][64 * 64];
    __shared__ float red[8];
    const int tid = threadIdx.x, lane = tid & 63, wid = tid >> 6;

    if (blockIdx.x >= 128) {
        // ---- bitmask + CSR row + fused deg/cbf ----
        const int row = blockIdx.x - 128;
        const float* ar = adj + (size_t)row * NN;
        const int j0 = tid * 8;
        f32x4 a0 = *(const f32x4*)(ar + j0), a1 = *(const f32x4*)(ar + j0 + 4);
        float s = a0[0] + a0[1] + a0[2] + a0[3] + a1[0] + a1[1] + a1[2] + a1[3];
        #pragma unroll
        for (int o = 32; o; o >>= 1) s += __shfl_down(s, o);
        if (lane == 0) red[wid] = s;
        __syncthreads();
        const float t = red[0] + red[1] + red[2] + red[3];   // exact integer
        if (tid == 0) {
            deg[row] = t;
            cbf[row] = bf2f(f2bf(0.75f * (1.0f / t)));       // == M's stored value
        }
        unsigned bb = 0;
        #pragma unroll
        for (int j = 0; j < 4; j++) bb |= (a0[j] > 0.f) ? (1u << j) : 0u;
        #pragma unroll
        for (int j = 0; j < 4; j++) bb |= (a1[j] > 0.f) ? (1u << (4 + j)) : 0u;
        BMb[(size_t)row * 256 + lane * 4 + wid] = (unsigned char)bb;

        // ordered compaction (ascending j): 256-thread scan
        int* wsumi = (int*)&Bs[0][0];          // alias (GEMM branch not taken)
        const int cnt = __popc(bb);
        int sc = cnt;
        #pragma unroll
        for (int o = 1; o < 64; o <<= 1) {
            const int tt = __shfl_up(sc, o);
            if (lane >= o) sc += tt;
        }
        if (lane == 63) wsumi[wid] = sc;
        __syncthreads();
        int base = 0;
        #pragma unroll
        for (int w = 0; w < 4; w++) if (w < wid) base += wsumi[w];
        int pos = base + sc - cnt;
        #pragma unroll
        for (int e = 0; e < 8; e++)
            if ((bb & (1u << e)) && pos < 128) CSRc[(size_t)row * 128 + pos++] = (u16)(j0 + e);
        if (tid == 0) {
            int Lt = wsumi[0] + wsumi[1] + wsumi[2] + wsumi[3];
            NL[row] = (Lt > 128) ? 128 : Lt;
        }
        return;
    }

    // ---- HW = h @ W tile (64x64, K=512) with f32->bf16 reg-staging ----
    const int b2 = blockIdx.x;
    const int trow = (b2 >> 2) * 64, tcol = (b2 & 3) * 64;
    const int wrow = (wid >> 1) * 32, wcol = (wid & 1) * 32;
    const int lrow = lane & 15, lq = lane >> 4;

    const int arow = tid >> 2, aq = tid & 3;
    auto stageA = [&](int k0, int buf) {
        const float* hp = h + (size_t)(trow + arow) * 512 + k0 + aq * 16;
        f32x4 v0 = *(const f32x4*)hp;
        f32x4 v1 = *(const f32x4*)(hp + 4);
        f32x4 v2 = *(const f32x4*)(hp + 8);
        f32x4 v3 = *(const f32x4*)(hp + 12);
        union { u16 h[8]; uint4 q; } o0, o1;
        #pragma unroll
        for (int j = 0; j < 4; j++) {
            o0.h[j] = f2bf(v0[j]); o0.h[4 + j] = f2bf(v1[j]);
            o1.h[j] = f2bf(v2[j]); o1.h[4 + j] = f2bf(v3[j]);
        }
        const int g0 = aq * 2;
        *(uint4*)&As[buf][arow * 64 + (g0 ^ (arow & 7)) * 8]       = o0.q;
        *(uint4*)&As[buf][arow * 64 + ((g0 + 1) ^ (arow & 7)) * 8] = o1.q;
    };
    const int bcol = tid >> 2, bq = tid & 3;
    auto stageB = [&](int k0, int buf) {
        union { u16 h[8]; uint4 q; } o0, o1;
        #pragma unroll
        for (int j = 0; j < 8; j++) {
            o0.h[j] = f2bf(W[(size_t)(k0 + bq * 16 + j) * 256 + tcol + bcol]);
            o1.h[j] = f2bf(W[(size_t)(k0 + bq * 16 + 8 + j) * 256 + tcol + bcol]);
        }
        const int g0 = bq * 2;
        *(uint4*)&Bs[buf][bcol * 64 + (g0 ^ (bcol & 7)) * 8]       = o0.q;
        *(uint4*)&Bs[buf][bcol * 64 + ((g0 + 1) ^ (bcol & 7)) * 8] = o1.q;
    };

    f32x4 acc[2][2] = {};
    stageA(0, 0); stageB(0, 0);
    __syncthreads();
    for (int ks = 0; ks < 8; ks++) {
        const int cur = ks & 1;
        if (ks < 7) { stageA((ks + 1) * 64, cur ^ 1); stageB((ks + 1) * 64, cur ^ 1); }
        bf16x8 af[2][2], bfv[2][2];
        #pragma unroll
        for (int kk = 0; kk < 2; kk++) {
            const int gsz = ((kk * 4 + lq) ^ (lrow & 7)) * 8;
            #pragma unroll
            for (int m = 0; m < 2; m++) {
                af[m][kk]  = *(const bf16x8*)&As[cur][(wrow + m * 16 + lrow) * 64 + gsz];
                bfv[m][kk] = *(const bf16x8*)&Bs[cur][(wcol + m * 16 + lrow) * 64 + gsz];
            }
        }
        #pragma unroll
        for (int kk = 0; kk < 2; kk++)
            #pragma unroll
            for (int m = 0; m < 2; m++)
                #pragma unroll
                for (int n = 0; n < 2; n++)
                    acc[m][n] = __builtin_amdgcn_mfma_f32_16x16x32_bf16(
                        af[m][kk], bfv[n][kk], acc[m][n], 0, 0, 0);
        __syncthreads();
    }
    float* hred = (float*)&As[0][0];   // alias (K-loop done, barrier passed)
    const int crow0 = trow + wrow + lq * 4;
    const int ccol0 = tcol + wcol + lrow;
    float av1[2], av2[2];
    #pragma unroll
    for (int n = 0; n < 2; n++) {
        av1[n] = av[ccol0 + n * 16];
        av2[n] = av[256 + ccol0 + n * 16];
    }
    #pragma unroll
    for (int m = 0; m < 2; m++) {
        #pragma unroll
        for (int r = 0; r < 4; r++) {
            float s1 = 0.f, s2 = 0.f;
            #pragma unroll
            for (int n = 0; n < 2; n++) {
                const float v = acc[m][n][r];
                HW[(size_t)(crow0 + m * 16 + r) * 256 + ccol0 + n * 16] = v;
                s1 += v * av1[n];
                s2 += v * av2[n];
            }
            #pragma unroll
            for (int o = 1; o < 16; o <<= 1) {
                s1 += __shfl_xor(s1, o);
                s2 += __shfl_xor(s2, o);
            }
            if (lrow == 0) {
                const int rl = wrow + lq * 4 + m * 16 + r;
                hred[rl * 4 + (wid & 1) * 2 + 0] = s1;
                hred[rl * 4 + (wid & 1) * 2 + 1] = s2;
            }
        }
    }
    __syncthreads();
    if (tid < 64) {
        h1part[(size_t)(b2 & 3) * NN + trow + tid] = hred[tid * 4 + 0] + hred[tid * 4 + 2];
        h2part[(size_t)(b2 & 3) * NN + trow + tid] = hred[tid * 4 + 1] + hred[tid * 4 + 3];
    }
}

// ---------------- wave reduce helpers ----------------
__device__ __forceinline__ int wred_sum_i(int v) {
    #pragma unroll
    for (int o = 32; o; o >>= 1) v += __shfl_down(v, o);
    return __shfl(v, 0);
}
__device__ __forceinline__ float wred_sum_f(float v) {
    #pragma unroll
    for (int o = 32; o; o >>= 1) v += __shfl_down(v, o);
    return __shfl(v, 0);
}
__device__ __forceinline__ float wred_max_f(float v) {
    #pragma unroll
    for (int o = 32; o; o >>= 1) v = fmaxf(v, __shfl_down(v, o));
    return __shfl(v, 0);
}

// ---------------- mega: CSR + LDS-BM neighbor-only P + softmax + out -------------
__global__ __launch_bounds__(64)
void mega_kernel(const u32* __restrict__ BM, const float* __restrict__ cbf,
                 const u16* __restrict__ CSRc, const int* __restrict__ NL,
                 const float* __restrict__ HW,
                 const float* __restrict__ h1p, const float* __restrict__ h2p,
                 const float* __restrict__ degv,
                 const float* __restrict__ a_ppr_p, float* __restrict__ out) {
    __shared__ u32   WBM[32][64];     // 8 KB: neighbor bitmask rows (typ. L<=32)
    __shared__ int   nidx_[128];
    __shared__ float nmv_[128];
    __shared__ float pval_[128];
    __shared__ float nval_[128];
    __shared__ float hsum_[128];
    const int lane = threadIdx.x;
    const int row = blockIdx.x;
    const float wi = cbf[row];
    const int L = NL[row];

    // ---- Phase A: CSR load (parallel, no scan) ----
    const bool vA = (lane < L), vB = (lane + 64 < L);
    int jA = 0, jB = 0;
    if (vA) jA = CSRc[(size_t)row * 128 + lane];
    if (vB) jB = CSRc[(size_t)row * 128 + 64 + lane];
    if (vA) { nidx_[lane] = jA; nmv_[lane] = cbf[jA]; }
    if (vB) { nidx_[lane + 64] = jB; nmv_[lane + 64] = cbf[jB]; }
    __syncthreads();

    // ---- pre-issue h2p gathers (overlap WBM fill + phase B); same add order ----
    if (vA) hsum_[lane]      = h2p[jA] + h2p[NN + jA] + h2p[2 * NN + jA] + h2p[3 * NN + jA];
    if (vB) hsum_[lane + 64] = h2p[jB] + h2p[NN + jB] + h2p[2 * NN + jB] + h2p[3 * NN + jB];
    const float h1r = h1p[row] + h1p[NN + row] + h1p[2 * NN + row] + h1p[3 * NN + row];

    // ---- preload neighbor BM rows: STATIC 32-slot bulk issue into registers ----
    const int Lp = (L < 32) ? L : 32;
    u32 wtmp[32];
    #pragma unroll
    for (int kk = 0; kk < 32; kk++)
        wtmp[kk] = (kk < Lp) ? BM[(size_t)nidx_[kk] * 64 + lane] : 0u;
    #pragma unroll
    for (int kk = 0; kk < 32; kk++)
        if (kk < Lp) WBM[kk][lane] = wtmp[kk];
    __syncthreads();

    // ---- Phase B: per-neighbor P; word read straight from LDS ----
    const int wAi = (jA >> 3) & 63, bAi = ((jA >> 9) << 3) | (jA & 7);
    const int wBi = (jB >> 3) & 63, bBi = ((jB >> 9) << 3) | (jB & 7);
    float pA = wi; if (vA && jA == row) pA += 1.f;
    float pB = wi; if (vB && jB == row) pB += 1.f;
    for (int kk = 0; kk < Lp; kk++) {
        const float ck = nmv_[kk];
        const u32 wordA = WBM[kk][wAi];
        const u32 wordB = WBM[kk][wBi];
        pA = fmaf(wi, ((wordA >> bAi) & 1u) ? ck : 0.f, pA);
        pB = fmaf(wi, ((wordB >> bBi) & 1u) ? ck : 0.f, pB);
    }
    for (int kk = Lp; kk < L; kk++) {          // rare L>32 tail: direct loads
        const float ck = nmv_[kk];
        const u32* rp = BM + (size_t)nidx_[kk] * 64;
        pA = fmaf(wi, ((rp[wAi] >> bAi) & 1u) ? ck : 0.f, pA);
        pB = fmaf(wi, ((rp[wBi] >> bBi) & 1u) ? ck : 0.f, pB);
    }
    pA *= 0.25f; pB *= 0.25f;
    if (vA) pval_[lane] = pA;
    if (vB) pval_[lane + 64] = pB;

    // ---- cut: skip when L<=32; L>32: bisection over neighbor values ----
    float cut = -1.0f;
    int tsel = 32, te = 0;
    if (L > 32) {
        unsigned lo = 0u, hi = 0x40000000u;   // [0, 2.0)
        while (hi - lo > 1u) {
            const unsigned mid = (lo + hi) >> 1;
            const float mf = __uint_as_float(mid);
            int c = (vA && pA >= mf) + (vB && pB >= mf);
            c = wred_sum_i(c);
            if (c >= 32) lo = mid; else hi = mid;
        }
        cut = __uint_as_float(lo);
        int mg = (vA && pA > cut) + (vB && pB > cut);
        int t2 = (vA && pA == cut) + (vB && pB == cut);
        mg = wred_sum_i(mg);
        te = wred_sum_i(t2);
        tsel = 32 - mg;
    }

    __syncthreads();   // pval + hsum visible across lanes

    // ---- out-gather prefetch (8-deep, static names) issued BEFORE softmax ----
    f32x4 hv0 = {0,0,0,0}, hv1 = {0,0,0,0}, hv2 = {0,0,0,0}, hv3 = {0,0,0,0};
    f32x4 hv4 = {0,0,0,0}, hv5 = {0,0,0,0}, hv6 = {0,0,0,0}, hv7 = {0,0,0,0};
    if (L > 0) hv0 = *(const f32x4*)(HW + (size_t)nidx_[0] * 256 + lane * 4);
    if (L > 1) hv1 = *(const f32x4*)(HW + (size_t)nidx_[1] * 256 + lane * 4);
    if (L > 2) hv2 = *(const f32x4*)(HW + (size_t)nidx_[2] * 256 + lane * 4);
    if (L > 3) hv3 = *(const f32x4*)(HW + (size_t)nidx_[3] * 256 + lane * 4);
    if (L > 4) hv4 = *(const f32x4*)(HW + (size_t)nidx_[4] * 256 + lane * 4);
    if (L > 5) hv5 = *(const f32x4*)(HW + (size_t)nidx_[5] * 256 + lane * 4);
    if (L > 6) hv6 = *(const f32x4*)(HW + (size_t)nidx_[6] * 256 + lane * 4);
    if (L > 7) hv7 = *(const f32x4*)(HW + (size_t)nidx_[7] * 256 + lane * 4);

    // ---- e values for neighbors, wave softmax ----
    const float dgr = degv[row];
    const float apr = a_ppr_p[0];
    float mymax = -3.0e38f;
    for (int k = lane; k < L; k += 64) {
        const int j = nidx_[k];
        const float p = pval_[k];
        bool sel = p > cut;
        if (!sel && p == cut) {
            if (tsel >= te) sel = true;
            else {                           // rare: low-index ties over neighbors
                int rk = 0;
                for (int q = 0; q < k; q++) rk += (pval_[q] == cut);
                sel = (rk < tsel);
            }
        }
        const float pprv = sel ? p * sqrtf(dgr / degv[j]) : 0.f;
        float e = h1r + hsum_[k] + apr * pprv;
        e = (e > 0.f) ? e : 0.2f * e;        // leaky_relu 0.2
        nval_[k] = e;
        mymax = fmaxf(mymax, e);
    }
    const float mx = wred_max_f(mymax);
    float mysum = 0.f;
    for (int k = lane; k < L; k += 64) {
        const float ev = expf(nval_[k] - mx);
        nval_[k] = ev;
        mysum += ev;
    }
    const float inv = 1.f / wred_sum_f(mysum);

    __syncthreads();   // nval visible across lanes

    // ---- out[row,:] = sum_k att_k * HW[j_k,:]; 8-deep rotating prefetch ----
    f32x4 acc = {0.f, 0.f, 0.f, 0.f};
    for (int k = 0; k < L; k++) {
        const f32x4 cur = hv0;
        hv0 = hv1; hv1 = hv2; hv2 = hv3; hv3 = hv4;
        hv4 = hv5; hv5 = hv6; hv6 = hv7;
        if (k + 8 < L) hv7 = *(const f32x4*)(HW + (size_t)nidx_[k + 8] * 256 + lane * 4);
        acc += (nval_[k] * inv) * cur;
    }
    *(f32x4*)(out + (size_t)row * 256 + lane * 4) = acc;
}

// ---------------- host ----------------
extern "C" void kernel_launch(void* const* d_in, const int* in_sizes, int n_in,
                              void* d_out, int out_size, void* d_ws, size_t ws_size,
                              hipStream_t stream) {
    const float* h     = (const float*)d_in[0];   // [2048,512]
    const float* adj   = (const float*)d_in[1];   // [2048,2048]
    const float* W     = (const float*)d_in[2];   // [512,256]
    const float* a     = (const float*)d_in[3];   // [512,1]
    const float* a_ppr = (const float*)d_in[4];   // [1,1]
    float* out = (float*)d_out;

    char* ws = (char*)d_ws;
    auto alloc = [&](size_t bytes) { char* p = ws; ws += (bytes + 255) & ~(size_t)255; return p; };
    unsigned char* BMb = (unsigned char*)alloc((size_t)NN * 256);   // 512 KB
    u16*   CSRc   = (u16*)  alloc((size_t)NN * 128 * 2);            // 512 KB
    int*   NL     = (int*)  alloc(NN * 4);
    float* cbf    = (float*)alloc(NN * 4);
    float* HW     = (float*)alloc((size_t)NN * 256 * 4);
    float* deg    = (float*)alloc(NN * 4);
    float* h1part = (float*)alloc((size_t)4 * NN * 4);
    float* h2part = (float*)alloc((size_t)4 * NN * 4);

    build_kernel<<<2176, 256, 0, stream>>>(adj, h, W, a, BMb, CSRc, NL, cbf, deg,
                                           HW, h1part, h2part);
    mega_kernel<<<NN, 64, 0, stream>>>((const u32*)BMb, cbf, CSRc, NL, HW,
                                       h1part, h2part, deg, a_ppr, out);
}